// Round 1
// 504.017 us; speedup vs baseline: 1.1311x; 1.1311x over previous
//
#include <hip/hip_runtime.h>
#include <cmath>

#define S 512
#define B 256
#define IN 64
#define H 256
#define HPAD 20    // h_buf row stride (16B-aligned rows, 2-way banks max)

// 256 blocks (one batch row) x 512 threads (8 waves, 2/SIMD).
// Thread (s = tid&15, jg = tid>>4) computes partials for 8 outputs
// j = 8*jg + r over k-slice [16s,16s+16) of h and [4s,4s+4) of x.
// The 16 partials of each output live in one 16-lane DPP row -> 4 fused
// cross-lane adds reduce them in-register (no LDS scatter, no reduce
// phase, ONE barrier per step with double-buffered h/x).
template<int CTRL>
__device__ __forceinline__ float dpp_add(float v) {
    int t = __builtin_amdgcn_update_dpp(0, __float_as_int(v), CTRL, 0xF, 0xF, true);
    return v + __int_as_float(t);
}

__global__ __launch_bounds__(512, 2) void rnn_fused4(
    const float* __restrict__ x,   // [S,B,IN]
    const float* __restrict__ Wx,  // [H,IN]
    const float* __restrict__ bx,  // [H]
    const float* __restrict__ Wh,  // [H,H]
    const float* __restrict__ bh,  // [H]
    float* __restrict__ out)       // [S,B,H] ++ [1,B,H]
{
    __shared__ __align__(16) float h_buf[2][16 * HPAD];
    __shared__ __align__(16) float x_buf[2][IN];

    const int tid = threadIdx.x;
    const int s   = tid & 15;      // k-slice, DPP-row-minor
    const int jg  = tid >> 4;      // output group [0,32)
    const int b   = blockIdx.x;

    // ---- one-time weight load: rows j = 8*jg + r ----
    float4 wh[8][4];
    float4 wx[8];
    #pragma unroll
    for (int r = 0; r < 8; ++r) {
        const int j = 8 * jg + r;
        const float4* whp = (const float4*)(Wh + (size_t)j * H + 16 * s);
        #pragma unroll
        for (int q = 0; q < 4; ++q) wh[r][q] = whp[q];
        wx[r] = *(const float4*)(Wx + (size_t)j * IN + 4 * s);
    }
    // pin in registers: opaque defs, not rematerializable
    #pragma unroll
    for (int r = 0; r < 8; ++r) {
        #pragma unroll
        for (int q = 0; q < 4; ++q)
            asm volatile("" : "+v"(wh[r][q].x), "+v"(wh[r][q].y),
                              "+v"(wh[r][q].z), "+v"(wh[r][q].w));
        asm volatile("" : "+v"(wx[r].x), "+v"(wx[r].y),
                          "+v"(wx[r].z), "+v"(wx[r].w));
    }

    const int jown = 8 * jg + (s & 7);          // output this lane finalizes
    const float bias = bh[jown] + bx[jown];

    // ---- init h=0, stage x(0) ----
    if (tid < 16 * HPAD) h_buf[0][tid] = 0.f;
    const float4* xsrc = (const float4*)(x + (size_t)b * IN) + tid;
    if (tid < 16) {
        ((float4*)x_buf[0])[tid] = *xsrc;
        xsrc += (B * IN) / 4;                   // -> x(1)
    }

    // s<8 writers: j = 8*jg + s
    const int jw    = 8 * jg + s;
    const int hwoff = (jw >> 4) * HPAD + (jw & 15);
    float* outp = out + (size_t)b * H + jw;
    float last_h = 0.f;

    __syncthreads();

    int p = 0;
    for (int t = 0; t < S; ++t) {
        // slice reads: 4+1 b128, broadcast, <=2-way banks (free)
        const float4 xv = ((const float4*)x_buf[p])[s];
        const float4* hb = (const float4*)(h_buf[p] + HPAD * s);
        const float4 h0 = hb[0], h1 = hb[1], h2 = hb[2], h3 = hb[3];

        // prefetch x(t+1) (latency hidden under FMAs)
        float4 xn;
        const bool pf = (tid < 16) && (t < S - 1);
        if (pf) { xn = *xsrc; xsrc += (B * IN) / 4; }

        // 160 FMAs, dep-distance 8 (r-inner per component)
        float acc[8];
        #pragma unroll
        for (int r = 0; r < 8; ++r) acc[r]  = wx[r].x * xv.x;
        #pragma unroll
        for (int r = 0; r < 8; ++r) acc[r] += wx[r].y * xv.y;
        #pragma unroll
        for (int r = 0; r < 8; ++r) acc[r] += wx[r].z * xv.z;
        #pragma unroll
        for (int r = 0; r < 8; ++r) acc[r] += wx[r].w * xv.w;

        #pragma unroll
        for (int q = 0; q < 4; ++q) {
            const float4 hq = (q == 0) ? h0 : (q == 1) ? h1 : (q == 2) ? h2 : h3;
            #pragma unroll
            for (int r = 0; r < 8; ++r) acc[r] += wh[r][q].x * hq.x;
            #pragma unroll
            for (int r = 0; r < 8; ++r) acc[r] += wh[r][q].y * hq.y;
            #pragma unroll
            for (int r = 0; r < 8; ++r) acc[r] += wh[r][q].z * hq.z;
            #pragma unroll
            for (int r = 0; r < 8; ++r) acc[r] += wh[r][q].w * hq.w;
        }

        // 16-lane butterfly: all lanes of the row end with the full sum.
        // MUST run with full exec (convergent DPP) - kept outside the if.
        #pragma unroll
        for (int r = 0; r < 8; ++r) {
            float v = acc[r];
            v = dpp_add<0xB1>(v);    // quad_perm [1,0,3,2] : + lane^1
            v = dpp_add<0x4E>(v);    // quad_perm [2,3,0,1] : + lane^2
            v = dpp_add<0x141>(v);   // row_half_mirror     : + other quad
            v = dpp_add<0x140>(v);   // row_mirror          : + other half
            acc[r] = v;
        }

        // lane s (mod 8) takes output r = s&7: 3-level cndmask tree
        const int rs = s & 7;
        const float v0 = (rs & 1) ? acc[1] : acc[0];
        const float v1 = (rs & 1) ? acc[3] : acc[2];
        const float v2 = (rs & 1) ? acc[5] : acc[4];
        const float v3 = (rs & 1) ? acc[7] : acc[6];
        const float w0 = (rs & 2) ? v1 : v0;
        const float w1 = (rs & 2) ? v3 : v2;
        const float u  = (rs & 4) ? w1 : w0;

        if (s < 8) {
            const float sum = u + bias;
            const float pre = fminf(fmaxf(sum, -15.f), 15.f);   // v_med3
            const float e   = __expf(2.f * pre);
            const float hv  = (e - 1.f) * __builtin_amdgcn_rcpf(e + 1.f);
            last_h = hv;
            h_buf[p ^ 1][hwoff] = hv;
            *outp = hv;                  // 32 consecutive floats per wave
            outp += B * H;
        }
        if (pf) ((float4*)x_buf[p ^ 1])[tid] = xn;

        __syncthreads();                 // ONE barrier per step
        p ^= 1;
    }

    if (s < 8)
        out[(size_t)S * B * H + (size_t)b * H + jw] = last_h;
}

extern "C" void kernel_launch(void* const* d_in, const int* in_sizes, int n_in,
                              void* d_out, int out_size, void* d_ws, size_t ws_size,
                              hipStream_t stream) {
    const float* x  = (const float*)d_in[0];
    const float* Wx = (const float*)d_in[1];
    const float* bx = (const float*)d_in[2];
    const float* Wh = (const float*)d_in[3];
    const float* bh = (const float*)d_in[4];
    float* out = (float*)d_out;

    rnn_fused4<<<dim3(B), dim3(512), 0, stream>>>(x, Wx, bx, Wh, bh, out);
}

// Round 2
// 488.187 us; speedup vs baseline: 1.1678x; 1.0324x over previous
//
#include <hip/hip_runtime.h>
#include <cmath>

#define S 512
#define B 256
#define IN 64
#define H 256
#define HPAD 20    // h_buf row stride (16B-aligned rows, 2-way banks max)

typedef float v2f __attribute__((ext_vector_type(2)));
typedef float v4f __attribute__((ext_vector_type(4)));

// 256 blocks (one batch row) x 512 threads (8 waves, 2/SIMD).
// Thread (s = tid&15, jg = tid>>4) computes partials for 8 outputs
// j = 8*jg + r over k-slice [16s,16s+16) of h and [4s,4s+4) of x.
// v_pk_fma_f32 (full-rate packed FP32 on CDNA) does 2 k-elems per
// instruction: 80 VOP3P replace 160 v_fmac. The 16-lane reduction runs
// 2 pure mirror stages then 2 reduce-AND-select quad_perm stages, so the
// final per-lane output pick costs 1 cndmask instead of a 7-op tree.

// DPP broadcast-mov (bound_ctrl=1, full masks): feeds a following add;
// GCNDPPCombine folds mov_dpp+add into v_add_f32_dpp.
template<int CTRL>
__device__ __forceinline__ float dpp_mov(float v) {
    return __int_as_float(__builtin_amdgcn_update_dpp(
        0, __float_as_int(v), CTRL, 0xF, 0xF, true));
}

// reduce-and-select stage over exact xor distance (quad_perm ctrl):
// lanes with `hi` keep b's running sum, others keep a's.
template<int CTRL>
__device__ __forceinline__ float comb(bool hi, float a, float b) {
    const float u = hi ? b : a;
    const float w = hi ? a : b;
    return u + dpp_mov<CTRL>(w);
}

#define PK_MUL(d, a, b) \
    asm("v_pk_mul_f32 %0, %1, %2" : "=v"(d) : "v"(a), "v"(b))
#define PK_FMA(d, a, b) \
    asm("v_pk_fma_f32 %0, %1, %2, %0" : "+v"(d) : "v"(a), "v"(b))

__global__ __launch_bounds__(512, 2) void rnn_fused5(
    const float* __restrict__ x,   // [S,B,IN]
    const float* __restrict__ Wx,  // [H,IN]
    const float* __restrict__ bx,  // [H]
    const float* __restrict__ Wh,  // [H,H]
    const float* __restrict__ bh,  // [H]
    float* __restrict__ out)       // [S,B,H] ++ [1,B,H]
{
    __shared__ __align__(16) float h_buf[2][16 * HPAD];
    __shared__ __align__(16) float x_buf[2][IN];

    const int tid = threadIdx.x;
    const int s   = tid & 15;      // k-slice, DPP-row-minor
    const int jg  = tid >> 4;      // output group [0,32)
    const int b   = blockIdx.x;

    // ---- one-time weight load as packed pairs: rows j = 8*jg + r ----
    v2f wh2[8][8];                 // 16 k-elems as 8 pairs
    v2f wx2[8][2];                 // 4 x-elems as 2 pairs
    #pragma unroll
    for (int r = 0; r < 8; ++r) {
        const int j = 8 * jg + r;
        const v4f* whp = (const v4f*)(Wh + (size_t)j * H + 16 * s);
        #pragma unroll
        for (int q = 0; q < 4; ++q) {
            const v4f t = whp[q];
            wh2[r][2 * q]     = t.lo;
            wh2[r][2 * q + 1] = t.hi;
        }
        const v4f tx = *(const v4f*)(Wx + (size_t)j * IN + 4 * s);
        wx2[r][0] = tx.lo;
        wx2[r][1] = tx.hi;
    }
    // pin pairs in arch VGPRs (VOP3P reads VGPR pairs; opaque defs are
    // not rematerializable so the 160 floats stay live in-register)
    #pragma unroll
    for (int r = 0; r < 8; ++r)
        asm volatile("" : "+v"(wh2[r][0]), "+v"(wh2[r][1]), "+v"(wh2[r][2]),
                          "+v"(wh2[r][3]), "+v"(wh2[r][4]), "+v"(wh2[r][5]),
                          "+v"(wh2[r][6]), "+v"(wh2[r][7]),
                          "+v"(wx2[r][0]), "+v"(wx2[r][1]));

    const int jown = 8 * jg + (s & 7);          // output this lane finalizes
    const float bias = bh[jown] + bx[jown];
    const bool b0 = (s & 1) != 0;               // hoisted select masks
    const bool b1 = (s & 2) != 0;
    const bool b2 = (s & 4) != 0;

    // ---- init h=0, stage x(0) ----
    if (tid < 16 * HPAD) h_buf[0][tid] = 0.f;
    const v4f* xsrc = (const v4f*)(x + (size_t)b * IN) + tid;
    if (tid < 16) {
        ((v4f*)x_buf[0])[tid] = *xsrc;
        xsrc += (B * IN) / 4;                   // -> x(1)
    }

    // s<8 writers: j = 8*jg + s
    const int jw    = 8 * jg + s;
    const int hwoff = (jw >> 4) * HPAD + (jw & 15);
    float* outp = out + (size_t)b * H + jw;
    float last_h = 0.f;

    __syncthreads();

    int p = 0;
    for (int t = 0; t < S; ++t) {
        // slice reads: 4+1 b128, broadcast, <=2-way banks (free)
        const v4f xv = ((const v4f*)x_buf[p])[s];
        const v2f xlo = xv.lo, xhi = xv.hi;
        const v4f* hb = (const v4f*)(h_buf[p] + HPAD * s);
        v2f hh[8];
        #pragma unroll
        for (int q = 0; q < 4; ++q) {
            const v4f hq = hb[q];
            hh[2 * q]     = hq.lo;
            hh[2 * q + 1] = hq.hi;
        }

        // prefetch x(t+1) (latency hidden under FMAs)
        v4f xn;
        const bool pf = (tid < 16) && (t < S - 1);
        if (pf) { xn = *xsrc; xsrc += (B * IN) / 4; }

        // 80 packed FMAs (2 k-elems each), dep distance 8
        v2f acc2[8];
        #pragma unroll
        for (int r = 0; r < 8; ++r) PK_MUL(acc2[r], wx2[r][0], xlo);
        #pragma unroll
        for (int r = 0; r < 8; ++r) PK_FMA(acc2[r], wx2[r][1], xhi);
        #pragma unroll
        for (int k = 0; k < 8; ++k) {
            #pragma unroll
            for (int r = 0; r < 8; ++r) PK_FMA(acc2[r], wh2[r][k], hh[k]);
        }

        // collapse packed halves, then 16-lane reduce.
        // MUST run with full exec (convergent DPP) - kept outside ifs.
        float acc[8];
        #pragma unroll
        for (int r = 0; r < 8; ++r) acc[r] = acc2[r].x + acc2[r].y;
        #pragma unroll
        for (int r = 0; r < 8; ++r) acc[r] += dpp_mov<0x140>(acc[r]); // row_mirror (xor15)
        #pragma unroll
        for (int r = 0; r < 8; ++r) acc[r] += dpp_mov<0x141>(acc[r]); // half_mirror (xor7)
        // reduce-and-select: exact xor2 then xor1, halving live accs
        const float n0 = comb<0x4E>(b1, acc[0], acc[2]);
        const float n1 = comb<0x4E>(b1, acc[1], acc[3]);
        const float n4 = comb<0x4E>(b1, acc[4], acc[6]);
        const float n5 = comb<0x4E>(b1, acc[5], acc[7]);
        const float m0 = comb<0xB1>(b0, n0, n1);
        const float m4 = comb<0xB1>(b0, n4, n5);
        const float total = b2 ? m4 : m0;     // lane s holds output r = s&7

        if (s < 8) {
            const float sum = total + bias;
            const float pre = fminf(fmaxf(sum, -15.f), 15.f);   // v_med3
            const float e   = __expf(2.f * pre);
            const float hv  = (e - 1.f) * __builtin_amdgcn_rcpf(e + 1.f);
            last_h = hv;
            h_buf[p ^ 1][hwoff] = hv;
            *outp = hv;                  // 32 consecutive floats per wave
            outp += B * H;
        }
        if (pf) ((v4f*)x_buf[p ^ 1])[tid] = xn;

        __syncthreads();                 // ONE barrier per step
        p ^= 1;
    }

    if (s < 8)
        out[(size_t)S * B * H + (size_t)b * H + jw] = last_h;
}

extern "C" void kernel_launch(void* const* d_in, const int* in_sizes, int n_in,
                              void* d_out, int out_size, void* d_ws, size_t ws_size,
                              hipStream_t stream) {
    const float* x  = (const float*)d_in[0];
    const float* Wx = (const float*)d_in[1];
    const float* bx = (const float*)d_in[2];
    const float* Wh = (const float*)d_in[3];
    const float* bh = (const float*)d_in[4];
    float* out = (float*)d_out;

    rnn_fused5<<<dim3(B), dim3(512), 0, stream>>>(x, Wx, bx, Wh, bh, out);
}

// Round 5
// 473.607 us; speedup vs baseline: 1.2038x; 1.0308x over previous
//
#include <hip/hip_runtime.h>
#include <cmath>

#define S 512
#define B 256
#define IN 64
#define H 256
#define HPAD 20    // h_buf row stride (16B-aligned rows, 2-way banks max)

typedef float v2f __attribute__((ext_vector_type(2)));
typedef float v4f __attribute__((ext_vector_type(4)));

// 256 blocks (one batch row) x 1024 threads (16 waves, 4/SIMD).
// Thread (s = tid&15, jg = tid>>4 in [0,64)) computes partials for 4
// outputs j = 4*jg + r over k-slice [16s,16s+16) of h, [4s,4s+4) of x.
// Reduction order matters: pure mirror stages (xor7, xor15) MUST run
// before the reduce-and-select stages (xor2, xor1). Mirrors preserve
// the accumulator index per lane; selects make the held index
// lane-dependent, after which any pure cross-lane add would mix
// different outputs (the round-4 bug, absmax 1.94).

template<int CTRL>
__device__ __forceinline__ float dpp_mov(float v) {
    return __int_as_float(__builtin_amdgcn_update_dpp(
        0, __float_as_int(v), CTRL, 0xF, 0xF, true));
}

// reduce-and-select over exact xor distance (quad_perm ctrl):
// lane keeps acc[hi] and receives the SAME acc from its xor partner
// (the remote lane's inverted select passes what the local lane keeps).
template<int CTRL>
__device__ __forceinline__ float comb(bool hi, float a, float b) {
    const float u = hi ? b : a;
    const float w = hi ? a : b;
    return u + dpp_mov<CTRL>(w);
}

#define PK_MUL(d, a, b) \
    asm("v_pk_mul_f32 %0, %1, %2" : "=v"(d) : "v"(a), "v"(b))
#define PK_FMA(d, a, b) \
    asm("v_pk_fma_f32 %0, %1, %2, %0" : "+v"(d) : "v"(a), "v"(b))

__global__ __launch_bounds__(1024, 4) void rnn_fused7(
    const float* __restrict__ x,   // [S,B,IN]
    const float* __restrict__ Wx,  // [H,IN]
    const float* __restrict__ bx,  // [H]
    const float* __restrict__ Wh,  // [H,H]
    const float* __restrict__ bh,  // [H]
    float* __restrict__ out)       // [S,B,H] ++ [1,B,H]
{
    __shared__ __align__(16) float h_buf[2][16 * HPAD];
    __shared__ __align__(16) float x_buf[2][IN];

    const int tid = threadIdx.x;
    const int s   = tid & 15;      // k-slice, DPP-row-minor
    const int jg  = tid >> 4;      // output group [0,64)
    const int b   = blockIdx.x;

    // ---- one-time weight load as packed pairs: rows j = 4*jg + r ----
    v2f wh2[4][8];                 // 16 k-elems as 8 pairs
    v2f wx2[4][2];                 // 4 x-elems as 2 pairs
    #pragma unroll
    for (int r = 0; r < 4; ++r) {
        const int j = 4 * jg + r;
        const v4f* whp = (const v4f*)(Wh + (size_t)j * H + 16 * s);
        #pragma unroll
        for (int q = 0; q < 4; ++q) {
            const v4f t = whp[q];
            wh2[r][2 * q]     = t.lo;
            wh2[r][2 * q + 1] = t.hi;
        }
        const v4f tx = *(const v4f*)(Wx + (size_t)j * IN + 4 * s);
        wx2[r][0] = tx.lo;
        wx2[r][1] = tx.hi;
    }
    // pin pairs in arch VGPRs (opaque defs, not rematerializable)
    #pragma unroll
    for (int r = 0; r < 4; ++r)
        asm volatile("" : "+v"(wh2[r][0]), "+v"(wh2[r][1]), "+v"(wh2[r][2]),
                          "+v"(wh2[r][3]), "+v"(wh2[r][4]), "+v"(wh2[r][5]),
                          "+v"(wh2[r][6]), "+v"(wh2[r][7]),
                          "+v"(wx2[r][0]), "+v"(wx2[r][1]));

    const int jown = 4 * jg + (s & 3);          // output this lane finalizes
    const float bias = bh[jown] + bx[jown];
    const bool b0 = (s & 1) != 0;               // hoisted select masks
    const bool b1 = (s & 2) != 0;

    // ---- init h=0, stage x(0) ----
    if (tid < 16 * HPAD) h_buf[0][tid] = 0.f;
    const v4f* xsrc = (const v4f*)(x + (size_t)b * IN) + tid;
    if (tid < 16) {
        ((v4f*)x_buf[0])[tid] = *xsrc;
        xsrc += (B * IN) / 4;                   // -> x(1)
    }

    // s<4 writers: j = 4*jg + s (wave covers 16 consecutive outputs)
    const int jw    = 4 * jg + s;
    const int hwoff = (jw >> 4) * HPAD + (jw & 15);
    float* outp = out + (size_t)b * H + jw;
    float last_h = 0.f;

    __syncthreads();

    // 2x-unrolled main loop: buffer pointers are compile-time constant.
#define STEP(CUR, NXT, TT)                                                    \
    {                                                                         \
        const v4f xv = ((const v4f*)x_buf[CUR])[s];                           \
        const v4f* hbp = (const v4f*)(h_buf[CUR] + HPAD * s);                 \
        const v4f q0 = hbp[0], q1 = hbp[1], q2 = hbp[2], q3 = hbp[3];         \
        v2f hh[8];                                                            \
        hh[0] = q0.lo; hh[1] = q0.hi; hh[2] = q1.lo; hh[3] = q1.hi;           \
        hh[4] = q2.lo; hh[5] = q2.hi; hh[6] = q3.lo; hh[7] = q3.hi;           \
        v4f xn;                                                               \
        const bool pf = (tid < 16) && ((TT) < S - 1);                         \
        if (pf) { xn = *xsrc; xsrc += (B * IN) / 4; }                         \
        v2f acc2[4];                                                          \
        _Pragma("unroll")                                                     \
        for (int r = 0; r < 4; ++r) PK_MUL(acc2[r], wx2[r][0], xv.lo);        \
        _Pragma("unroll")                                                     \
        for (int r = 0; r < 4; ++r) PK_FMA(acc2[r], wx2[r][1], xv.hi);        \
        _Pragma("unroll")                                                     \
        for (int k = 0; k < 8; ++k) {                                         \
            _Pragma("unroll")                                                 \
            for (int r = 0; r < 4; ++r) PK_FMA(acc2[r], wh2[r][k], hh[k]);    \
        }                                                                     \
        float c[4];                                                           \
        _Pragma("unroll")                                                     \
        for (int r = 0; r < 4; ++r) c[r] = acc2[r].x + acc2[r].y;             \
        /* PURE mirrors first: index-preserving reduction over xor7,xor15 */  \
        _Pragma("unroll")                                                     \
        for (int r = 0; r < 4; ++r) c[r] += dpp_mov<0x141>(c[r]);             \
        _Pragma("unroll")                                                     \
        for (int r = 0; r < 4; ++r) c[r] += dpp_mov<0x140>(c[r]);             \
        /* THEN reduce-and-select: xor2, xor1 (quad_perm exact) */            \
        const float n0 = comb<0x4E>(b1, c[0], c[2]);                          \
        const float n1 = comb<0x4E>(b1, c[1], c[3]);                          \
        const float m  = comb<0xB1>(b0, n0, n1);  /* lane s: output s&3 */    \
        if (s < 4) {                                                          \
            const float sum = m + bias;                                       \
            const float pre = fminf(fmaxf(sum, -15.f), 15.f);                 \
            const float e   = __builtin_amdgcn_exp2f(pre * 2.88539008177793f);\
            const float hv  = (e - 1.f) * __builtin_amdgcn_rcpf(e + 1.f);     \
            last_h = hv;                                                      \
            h_buf[NXT][hwoff] = hv;                                           \
            *outp = hv;            /* 16 consecutive floats per wave */       \
            outp += B * H;                                                    \
        }                                                                     \
        if (pf) ((v4f*)x_buf[NXT])[tid] = xn;                                 \
        __syncthreads();                                                      \
    }

    for (int t2 = 0; t2 < S / 2; ++t2) {
        STEP(0, 1, 2 * t2);
        STEP(1, 0, 2 * t2 + 1);
    }
#undef STEP

    if (s < 4)
        out[(size_t)S * B * H + (size_t)b * H + jw] = last_h;
}

extern "C" void kernel_launch(void* const* d_in, const int* in_sizes, int n_in,
                              void* d_out, int out_size, void* d_ws, size_t ws_size,
                              hipStream_t stream) {
    const float* x  = (const float*)d_in[0];
    const float* Wx = (const float*)d_in[1];
    const float* bx = (const float*)d_in[2];
    const float* Wh = (const float*)d_in[3];
    const float* bh = (const float*)d_in[4];
    float* out = (float*)d_out;

    rnn_fused7<<<dim3(B), dim3(1024), 0, stream>>>(x, Wx, bx, Wh, bh, out);
}

// Round 7
// 468.636 us; speedup vs baseline: 1.2165x; 1.0106x over previous
//
#include <hip/hip_runtime.h>
#include <cmath>

#define S 512
#define B 256
#define IN 64
#define H 256

typedef float v2f __attribute__((ext_vector_type(2)));
typedef float v4f __attribute__((ext_vector_type(4)));
typedef __fp16 h2 __attribute__((ext_vector_type(2)));
typedef __fp16 h4 __attribute__((ext_vector_type(4)));
typedef __fp16 h8 __attribute__((ext_vector_type(8)));

// 256 blocks (one batch row) x 1024 threads (16 waves, 4/SIMD).
// Same mapping as the verified round-5 kernel: thread (s = tid&15,
// jg = tid>>4) computes 4 outputs j = 4*jg + r over k-slice
// [16s,16s+16) of h and [4s,4s+4) of x. Change: dot-product operands
// (Wh, Wx, h, x) are f16 and the MACs run on v_dot2_f32_f16 (full-rate,
// 2 f16 MACs/lane/instr at 2cyc vs v_pk_fma_f32's 4cyc) with f32
// accumulate. h-state math (reduction, tanh, global out) stays f32.
// h_buf rows [16][24] f16: 48B stride keeps ds_read_b128 16B-aligned
// and start banks 12s mod 32 -> <=2-way (free). Reduction order (pure
// mirrors xor7/xor15 FIRST, then reduce-and-select xor2/xor1) is the
// round-5-verified one. NOTE: half-vector types must be __fp16-based:
// __builtin_amdgcn_cvt_pkrtz / fdot2 use __fp16 ext-vectors, and
// _Float16 vectors are treated as an incompatible element type.

template<int CTRL>
__device__ __forceinline__ float dpp_mov(float v) {
    return __int_as_float(__builtin_amdgcn_update_dpp(
        0, __float_as_int(v), CTRL, 0xF, 0xF, true));
}

// reduce-and-select over exact xor distance (quad_perm ctrl)
template<int CTRL>
__device__ __forceinline__ float comb(bool hi, float a, float b) {
    const float u = hi ? b : a;
    const float w = hi ? a : b;
    return u + dpp_mov<CTRL>(w);
}

__device__ __forceinline__ float dot2(h2 a, h2 b, float c) {
    return __builtin_amdgcn_fdot2(a, b, c, false);
}

__global__ __launch_bounds__(1024, 4) void rnn_fused8b(
    const float* __restrict__ x,   // [S,B,IN]
    const float* __restrict__ Wx,  // [H,IN]
    const float* __restrict__ bx,  // [H]
    const float* __restrict__ Wh,  // [H,H]
    const float* __restrict__ bh,  // [H]
    float* __restrict__ out)       // [S,B,H] ++ [1,B,H]
{
    __shared__ __align__(16) __fp16 h_buf[2][16][24];    // 16 used +8 pad
    __shared__ __align__(16) h2 x_buf[2][32];            // 64 f16

    const int tid = threadIdx.x;
    const int s   = tid & 15;      // k-slice, DPP-row-minor
    const int jg  = tid >> 4;      // output group [0,64)
    const int b   = blockIdx.x;

    // ---- one-time weight load, f32 -> f16 pairs ----
    h2 wh2[4][8];                  // 16 h-weights as 8 f16-pairs
    h2 wx2[4][2];                  // 4 x-weights as 2 f16-pairs
    #pragma unroll
    for (int r = 0; r < 4; ++r) {
        const int j = 4 * jg + r;
        const v4f* whp = (const v4f*)(Wh + (size_t)j * H + 16 * s);
        #pragma unroll
        for (int q = 0; q < 4; ++q) {
            const v4f t = whp[q];
            wh2[r][2 * q]     = h2{(__fp16)t.x, (__fp16)t.y};
            wh2[r][2 * q + 1] = h2{(__fp16)t.z, (__fp16)t.w};
        }
        const v4f tx = *(const v4f*)(Wx + (size_t)j * IN + 4 * s);
        wx2[r][0] = h2{(__fp16)tx.x, (__fp16)tx.y};
        wx2[r][1] = h2{(__fp16)tx.z, (__fp16)tx.w};
    }
    // pin in VGPRs (opaque defs, not rematerializable)
    #pragma unroll
    for (int r = 0; r < 4; ++r)
        asm volatile("" : "+v"(wh2[r][0]), "+v"(wh2[r][1]), "+v"(wh2[r][2]),
                          "+v"(wh2[r][3]), "+v"(wh2[r][4]), "+v"(wh2[r][5]),
                          "+v"(wh2[r][6]), "+v"(wh2[r][7]),
                          "+v"(wx2[r][0]), "+v"(wx2[r][1]));

    const int jown = 4 * jg + (s & 3);          // output this lane finalizes
    const float bias = bh[jown] + bx[jown];
    const bool b0 = (s & 1) != 0;               // hoisted select masks
    const bool b1 = (s & 2) != 0;

    // ---- init h=0, stage x(0) as f16 ----
    if (tid < 256) h_buf[0][tid >> 4][tid & 15] = (__fp16)0.f;
    const v4f* xsrc = (const v4f*)(x + (size_t)b * IN) + tid;
    if (tid < 16) {
        const v4f x0 = *xsrc;
        x_buf[0][2 * tid]     = __builtin_amdgcn_cvt_pkrtz(x0.x, x0.y);
        x_buf[0][2 * tid + 1] = __builtin_amdgcn_cvt_pkrtz(x0.z, x0.w);
        xsrc += (B * IN) / 4;                   // -> x(1)
    }

    // s<4 writers: j = 4*jg + s (wave covers 16 consecutive outputs)
    const int jw    = 4 * jg + s;
    float* outp = out + (size_t)b * H + jw;
    float last_h = 0.f;

    __syncthreads();

    // 2x-unrolled main loop: buffer indices compile-time constant.
#define STEP(CUR, NXT, TT)                                                    \
    {                                                                         \
        const h4 xv = *(const h4*)&x_buf[CUR][2 * s];                         \
        const h8 A  = *(const h8*)&h_buf[CUR][s][0];   /* b128 */             \
        const h8 Bv = *(const h8*)&h_buf[CUR][s][8];   /* b128 */             \
        v4f xn;                                                               \
        const bool pf = (tid < 16) && ((TT) < S - 1);                         \
        if (pf) { xn = *xsrc; xsrc += (B * IN) / 4; }                         \
        float c[4];                                                           \
        _Pragma("unroll")                                                     \
        for (int r = 0; r < 4; ++r) {                                         \
            float a = dot2(wx2[r][0], xv.lo, 0.f);                            \
            a = dot2(wx2[r][1], xv.hi, a);                                    \
            a = dot2(wh2[r][0], A.lo.lo,  a);                                 \
            a = dot2(wh2[r][1], A.lo.hi,  a);                                 \
            a = dot2(wh2[r][2], A.hi.lo,  a);                                 \
            a = dot2(wh2[r][3], A.hi.hi,  a);                                 \
            a = dot2(wh2[r][4], Bv.lo.lo, a);                                 \
            a = dot2(wh2[r][5], Bv.lo.hi, a);                                 \
            a = dot2(wh2[r][6], Bv.hi.lo, a);                                 \
            a = dot2(wh2[r][7], Bv.hi.hi, a);                                 \
            c[r] = a;                                                         \
        }                                                                     \
        /* PURE mirrors first: index-preserving reduce over xor7,xor15 */     \
        _Pragma("unroll")                                                     \
        for (int r = 0; r < 4; ++r) c[r] += dpp_mov<0x141>(c[r]);             \
        _Pragma("unroll")                                                     \
        for (int r = 0; r < 4; ++r) c[r] += dpp_mov<0x140>(c[r]);             \
        /* THEN reduce-and-select: xor2, xor1 (quad_perm exact) */            \
        const float n0 = comb<0x4E>(b1, c[0], c[2]);                          \
        const float n1 = comb<0x4E>(b1, c[1], c[3]);                          \
        const float m  = comb<0xB1>(b0, n0, n1);  /* lane s: output s&3 */    \
        if (s < 4) {                                                          \
            const float sum = m + bias;                                       \
            const float pre = fminf(fmaxf(sum, -15.f), 15.f);                 \
            const float e   = __builtin_amdgcn_exp2f(pre * 2.88539008177793f);\
            const float hv  = (e - 1.f) * __builtin_amdgcn_rcpf(e + 1.f);     \
            last_h = hv;                                                      \
            h_buf[NXT][jw >> 4][jw & 15] = (__fp16)hv;    /* b16 write */     \
            *outp = hv;            /* 16 consecutive floats per wave */       \
            outp += B * H;                                                    \
        }                                                                     \
        if (pf) {                                                             \
            x_buf[NXT][2 * tid]     = __builtin_amdgcn_cvt_pkrtz(xn.x, xn.y); \
            x_buf[NXT][2 * tid + 1] = __builtin_amdgcn_cvt_pkrtz(xn.z, xn.w); \
        }                                                                     \
        __syncthreads();                                                      \
    }

    for (int t2 = 0; t2 < S / 2; ++t2) {
        STEP(0, 1, 2 * t2);
        STEP(1, 0, 2 * t2 + 1);
    }
#undef STEP

    if (s < 4)
        out[(size_t)S * B * H + (size_t)b * H + jw] = last_h;
}

extern "C" void kernel_launch(void* const* d_in, const int* in_sizes, int n_in,
                              void* d_out, int out_size, void* d_ws, size_t ws_size,
                              hipStream_t stream) {
    const float* x  = (const float*)d_in[0];
    const float* Wx = (const float*)d_in[1];
    const float* bx = (const float*)d_in[2];
    const float* Wh = (const float*)d_in[3];
    const float* bh = (const float*)d_in[4];
    float* out = (float*)d_out;

    rnn_fused8b<<<dim3(B), dim3(1024), 0, stream>>>(x, Wx, bx, Wh, bh, out);
}